// Round 13
// baseline (291.664 us; speedup 1.0000x reference)
//
#include <hip/hip_runtime.h>
#include <hip/hip_bf16.h>

typedef __hip_bfloat16 bf16;
typedef __attribute__((ext_vector_type(8))) short short8;
typedef __attribute__((ext_vector_type(4))) float floatx4;

__device__ __forceinline__ float b2f(bf16 v) { return __bfloat162float(v); }
__device__ __forceinline__ bf16 f2b(float v) { return __float2bfloat16(v); }
__device__ __forceinline__ float ldv(const void* p, size_t i, bool f32) {
    return f32 ? ((const float*)p)[i] : b2f(((const bf16*)p)[i]);
}
template <bool F32>
__device__ __forceinline__ float ldt(const void* p, size_t i) {
    return F32 ? ((const float*)p)[i] : b2f(((const bf16*)p)[i]);
}
__device__ __forceinline__ float s2f(short s) {
    unsigned int u = ((unsigned int)(unsigned short)s) << 16;
    float f; __builtin_memcpy(&f, &u, 4); return f;
}
__device__ __forceinline__ short f2s(float f) {
    bf16 h = f2b(f); short s; __builtin_memcpy(&s, &h, 2); return s;
}
__device__ __forceinline__ bool uflag(const int* flag) {
    return __builtin_amdgcn_readfirstlane(flag[0]) != 0;   // SGPR -> uniform branch
}
#define MFMA16(a, b, c) __builtin_amdgcn_mfma_f32_16x16x32_bf16(a, b, c, 0, 0, 0)

struct Ptrs { const void* p[45]; };

struct Lvl {
    const void *f1, *f2;
    const float *btgp, *wbf, *bfold;
    const bf16 *Wb, *Wt, *Wc3;
    bf16 *th, *g, *p, *phi, *gt, *yp, *z;
    float* lp;
    int N, n, npad, nch, W, s, wp, H, tX, BN;
    size_t outOff;
};

// per-level weight region layout (float offsets), stride LVS
#define O_BTGP  0
#define O_WBF   96
#define O_BFOLD 160
#define O_WT    192            // 2048 bf16 = 1024 floats
#define O_WC3   1216           // 18432 bf16 = 9216 floats
#define O_WB    10432          // 6144 bf16 = 3072 floats  (tgp weights [o][k])
#define LVS     13504

// ---------------- K0: weight prep + inline dtype detect (self-detect per block) ----------------
__global__ void k_prep(Ptrs in, int* flag, float* __restrict__ wsf)
{
    __shared__ int scnt;
    if (threadIdx.x == 0) scnt = 0;
    __syncthreads();
    {
        const unsigned short* us = (const unsigned short*)in.p[0];
        int local = 0;
        for (int i = threadIdx.x; i < 8192; i += 256) {
            unsigned e = us[2 * i] & 0x7F80u;
            if (e == 0x7F80u || e == 0u) local++;
        }
        atomicAdd(&scnt, local);
    }
    __syncthreads();
    bool f32 = scnt >= 8;
    if (blockIdx.x == 0 && blockIdx.y == 0 && threadIdx.x == 0) flag[0] = f32 ? 1 : 0;

    int lv = blockIdx.y;
    float* base = wsf + (size_t)lv * LVS;
    const int wb0 = 6 + 13 * lv;
    const void* gw  = in.p[wb0 + 0];
    const void* gb  = in.p[wb0 + 1];
    const void* tw  = in.p[wb0 + 2];
    const void* tb  = in.p[wb0 + 3];
    const void* pw  = in.p[wb0 + 4];
    const void* pb  = in.p[wb0 + 5];
    const void* ww  = in.p[wb0 + 6];
    const void* wb  = in.p[wb0 + 7];
    const void* cw  = in.p[wb0 + 8];
    const void* bng = in.p[wb0 + 9];
    const void* bnb = in.p[wb0 + 10];
    const void* bnm = in.p[wb0 + 11];
    const void* bnv = in.p[wb0 + 12];
    int gid = blockIdx.x * 256 + threadIdx.x;
    int stride = gridDim.x * 256;

    float* btgp = base + O_BTGP;
    float* wbf = base + O_WBF;
    float* bfold = base + O_BFOLD;
    bf16* Wt = (bf16*)(base + O_WT);
    bf16* Wc3 = (bf16*)(base + O_WC3);
    bf16* Wb = (bf16*)(base + O_WB);

    for (int e = gid; e < 96 * 64; e += stride) {
        int o = e >> 6, k = e & 63;
        float v;
        if (o < 32)      v = ldv(tw, (size_t)o * 64 + k, f32);
        else if (o < 64) v = ldv(gw, (size_t)(o - 32) * 64 + k, f32);
        else             v = ldv(pw, (size_t)(o - 64) * 64 + k, f32);
        Wb[e] = f2b(v);
    }
    for (int e = gid; e < 96; e += stride) {
        float v = (e < 32) ? ldv(tb, e, f32)
                           : (e < 64 ? ldv(gb, e - 32, f32) : ldv(pb, e - 64, f32));
        btgp[e] = v;
    }
    for (int e = gid; e < 64 * 32; e += stride)
        Wt[e] = f2b(ldv(ww, e, f32));
    for (int e = gid; e < 64; e += stride) wbf[e] = ldv(wb, e, f32);
    for (int e = gid; e < 18432; e += stride) {
        int k = e & 31, n = (e >> 5) & 15, ot = (e >> 9) & 1;
        int tap = (e >> 10) % 9, cc = e / 9216;
        int o = ot * 16 + n, c = cc * 32 + k;
        float inv = ldv(bng, o, f32) * rsqrtf(ldv(bnv, o, f32) + 1e-5f);
        Wc3[e] = f2b(ldv(cw, ((size_t)o * 64 + c) * 9 + tap, f32) * inv);
    }
    for (int e = gid; e < 32; e += stride) {
        float inv = ldv(bng, e, f32) * rsqrtf(ldv(bnv, e, f32) + 1e-5f);
        bfold[e] = ldv(bnb, e, f32) - ldv(bnm, e, f32) * inv;
    }
}

// ---------------- K1: MFMA theta/g/phi 1x1 conv (proven) ----------------
template <bool F32>
__device__ __forceinline__ void tgpm_body(const Lvl& P, int rb)
{
    __shared__ __align__(16) bf16 X[64 * 72];
    int tid = threadIdx.x, lane = tid & 63, wv = tid >> 6;
    int quad = lane >> 4, col = lane & 15;
    int row0 = rb * 64;
    int b = row0 / P.N;
    int pix0 = row0 - b * P.N;

#pragma unroll
    for (int it = 0; it < 16; it++) {
        int e = it * 256 + tid;
        int pix = e & 63, c = e >> 6;
        const void* fx = (c < 32) ? P.f1 : P.f2;
        int cc = c & 31;
        float v = ldt<F32>(fx, (size_t)(b * 32 + cc) * P.N + pix0 + pix);
        X[pix * 72 + c] = f2b(v);
    }
    __syncthreads();

    short8 a_lo = *(const short8*)(X + (wv * 16 + col) * 72 + quad * 8);
    short8 a_hi = *(const short8*)(X + (wv * 16 + col) * 72 + 32 + quad * 8);
    const floatx4 zc = {0.f, 0.f, 0.f, 0.f};
#pragma unroll
    for (int ot = 0; ot < 6; ot++) {
        const bf16* wp = P.Wb + (size_t)(ot * 16 + col) * 64 + quad * 8;
        short8 b_lo = *(const short8*)(wp);
        short8 b_hi = *(const short8*)(wp + 32);
        floatx4 acc = MFMA16(a_lo, b_lo, zc);
        acc = MFMA16(a_hi, b_hi, acc);
        float bias = P.btgp[ot * 16 + col];
        bf16* dst = (ot < 2) ? P.th : ((ot < 4) ? P.g : P.p);
        int och = (ot & 1) * 16 + col;
#pragma unroll
        for (int r = 0; r < 4; r++) {
            int pix = row0 + wv * 16 + quad * 4 + r;
            dst[(size_t)pix * 32 + och] = f2b(acc[r] + bias);
        }
    }
}

__global__ void k_tgpm(Lvl a0, Lvl a1, Lvl a2, int s1, int s2, const int* flag)
{
    int bid = blockIdx.x;
    const Lvl P = bid < s1 ? a0 : (bid < s2 ? a1 : a2);
    int rb = bid - (bid < s1 ? 0 : (bid < s2 ? s1 : s2));
    if (uflag(flag)) tgpm_body<true>(P, rb);
    else             tgpm_body<false>(P, rb);
}

// ---------------- K2: max pool -> phiB / gT (proven) ----------------
__global__ void k_pool(Lvl a0, Lvl a1, Lvl a2, int s1, int s2)
{
    int bid = blockIdx.x;
    const Lvl P = bid < s1 ? a0 : (bid < s2 ? a1 : a2);
    int local = bid - (bid < s1 ? 0 : (bid < s2 ? s1 : s2));
    int gid = local * 256 + threadIdx.x;
    int npad = P.npad;
    if (gid >= 4 * npad * 32) return;
    int c = gid & 31;
    int j = (gid >> 5) % npad;
    int b = gid / (32 * npad);
    float mg = 0.f, mp = 0.f;
    if (j < P.n) {
        int py = j / P.wp, px = j - py * P.wp;
        const int N = P.N;
        mg = -INFINITY; mp = -INFINITY;
        for (int dy = 0; dy < P.s; dy++)
            for (int dx = 0; dx < P.s; dx++) {
                int idx = (py * P.s + dy) * P.W + px * P.s + dx;
                size_t bse = ((size_t)b * N + idx) * 32 + c;
                mg = fmaxf(mg, b2f(P.g[bse]));
                mp = fmaxf(mp, b2f(P.p[bse]));
            }
    }
    P.phi[((size_t)b * npad + j) * 32 + c] = f2b(mp);
    P.gt[((size_t)b * 32 + c) * npad + j] = f2b(mg);
}

// ---------------- K3: MFMA attention, R7-exact inner loop (proven 72 us) ----------------
__launch_bounds__(256)
__global__ void k_attn(Lvl a0, Lvl a1, Lvl a2, int s1, int s2)
{
    __shared__ __align__(16) bf16 Pt_s[4 * 1152];
    int bid = blockIdx.x;
    const Lvl P = bid < s1 ? a0 : (bid < s2 ? a1 : a2);
    int local = bid - (bid < s1 ? 0 : (bid < s2 ? s1 : s2));
    int rowblocks = P.BN >> 6;
    int c = local / rowblocks;
    int rb = local - c * rowblocks;

    int tid = threadIdx.x, lane = tid & 63, wv = tid >> 6;
    int quad = lane >> 4, col = lane & 15;
    bf16* Pt = Pt_s + wv * 1152;
    int row0 = rb * 64;
    int b = row0 / P.N;
    int npad = P.npad;

    int T = npad >> 6, C = P.nch;
    int js = ((T * c) / C) << 6;
    int je = ((T * (c + 1)) / C) << 6;

    short8 ta = *(const short8*)(P.th + (size_t)(row0 + wv * 16 + col) * 32 + quad * 8);
    const bf16* php = P.phi + (size_t)b * npad * 32 + (size_t)col * 32 + quad * 8;
    const bf16* gtp = P.gt + (size_t)b * 32 * npad + (size_t)col * npad + quad * 8;

    floatx4 y0 = {0.f, 0.f, 0.f, 0.f}, y1 = {0.f, 0.f, 0.f, 0.f};
    float lp4[4] = {0.f, 0.f, 0.f, 0.f};
    const floatx4 zc = {0.f, 0.f, 0.f, 0.f};

    for (int j0 = js; j0 < je; j0 += 64) {
        floatx4 s0 = MFMA16(ta, *(const short8*)(php + (size_t)(j0 +  0) * 32), zc);
        floatx4 s1 = MFMA16(ta, *(const short8*)(php + (size_t)(j0 + 16) * 32), zc);
        floatx4 s2 = MFMA16(ta, *(const short8*)(php + (size_t)(j0 + 32) * 32), zc);
        floatx4 s3 = MFMA16(ta, *(const short8*)(php + (size_t)(j0 + 48) * 32), zc);
#pragma unroll
        for (int r = 0; r < 4; r++) {
            float p0 = __expf(s0[r]), p1 = __expf(s1[r]);
            float p2 = __expf(s2[r]), p3 = __expf(s3[r]);
            lp4[r] += (p0 + p1) + (p2 + p3);
            bf16* pr = Pt + (quad * 4 + r) * 72;
            pr[ 0 + col] = f2b(p0);
            pr[16 + col] = f2b(p1);
            pr[32 + col] = f2b(p2);
            pr[48 + col] = f2b(p3);
        }
#pragma unroll
        for (int kc = 0; kc < 2; kc++) {
            short8 pa = *(const short8*)(Pt + col * 72 + kc * 32 + quad * 8);
            short8 g0 = *(const short8*)(gtp + j0 + kc * 32);
            short8 g1 = *(const short8*)(gtp + (size_t)16 * npad + j0 + kc * 32);
            y0 = MFMA16(pa, g0, y0);
            y1 = MFMA16(pa, g1, y1);
        }
    }

#pragma unroll
    for (int r = 0; r < 4; r++) {
        float v = lp4[r];
        v += __shfl_xor(v, 1); v += __shfl_xor(v, 2);
        v += __shfl_xor(v, 4); v += __shfl_xor(v, 8);
        int grow = row0 + wv * 16 + quad * 4 + r;
        size_t o = ((size_t)c * P.BN + grow) * 32;
        P.yp[o + col] = f2b(y0[r]);
        P.yp[o + 16 + col] = f2b(y1[r]);
        if (col == 0) P.lp[(size_t)c * P.BN + grow] = v;
    }
}

// ---------------- K4: merge partials + W-conv + residual -> z (proven) ----------------
__launch_bounds__(256)
__global__ void k_merge(Lvl a0, Lvl a1, Lvl a2, int s1, int s2, const int* flag)
{
    bool f32 = uflag(flag);
    __shared__ __align__(16) float zb[64 * 65];
    int bid = blockIdx.x;
    const Lvl P = bid < s1 ? a0 : (bid < s2 ? a1 : a2);
    int rb = bid - (bid < s1 ? 0 : (bid < s2 ? s1 : s2));
    int tid = threadIdx.x, lane = tid & 63, wv = tid >> 6;
    int quad = lane >> 4, col = lane & 15;
    int row0 = rb * 64;
    int b = row0 / P.N;
    int pix0 = row0 - b * P.N;

    int grow = row0 + wv * 16 + col;
    float yv[8] = {0.f, 0.f, 0.f, 0.f, 0.f, 0.f, 0.f, 0.f};
    float L = -(float)(P.npad - P.n);
    for (int cc = 0; cc < P.nch; cc++) {
        short8 v = *(const short8*)(P.yp + ((size_t)cc * P.BN + grow) * 32 + quad * 8);
#pragma unroll
        for (int j = 0; j < 8; j++) yv[j] += s2f(v[j]);
        L += P.lp[(size_t)cc * P.BN + grow];
    }
    float invL = 1.f / L;
    short8 ya;
#pragma unroll
    for (int j = 0; j < 8; j++) ya[j] = f2s(yv[j] * invL);

    const floatx4 zc = {0.f, 0.f, 0.f, 0.f};
    floatx4 zt[4];
#pragma unroll
    for (int ot = 0; ot < 4; ot++) {
        short8 wbv = *(const short8*)(P.Wt + (size_t)(ot * 16 + col) * 32 + quad * 8);
        zt[ot] = MFMA16(ya, wbv, zc);
    }
#pragma unroll
    for (int ot = 0; ot < 4; ot++)
#pragma unroll
        for (int r = 0; r < 4; r++)
            zb[(wv * 16 + quad * 4 + r) * 65 + ot * 16 + col] = zt[ot][r];
    __syncthreads();

    const void* fx = (wv < 2) ? P.f1 : P.f2;
    if (f32) {
#pragma unroll
        for (int k = 0; k < 16; k++) {
            int o = wv * 16 + k, op = o & 31;
            float a = zb[lane * 65 + o] + P.wbf[o];
            a += ((const float*)fx)[(size_t)(b * 32 + op) * P.N + pix0 + lane];
            P.z[((size_t)(b * 64 + o)) * P.N + pix0 + lane] = f2b(a);
        }
    } else {
#pragma unroll
        for (int k = 0; k < 16; k++) {
            int o = wv * 16 + k, op = o & 31;
            float a = zb[lane * 65 + o] + P.wbf[o];
            a += b2f(((const bf16*)fx)[(size_t)(b * 32 + op) * P.N + pix0 + lane]);
            P.z[((size_t)(b * 64 + o)) * P.N + pix0 + lane] = f2b(a);
        }
    }
}

// ---------------- K5: MFMA 3x3 conv, 8 waves chunk-parallel (proven) ----------------
__launch_bounds__(512)
__global__ void k_conv3m(Lvl a0, Lvl a1, Lvl a2, int s1, int s2,
                         void* out, const int* flag)
{
    bool f32 = uflag(flag);
    __shared__ __align__(16) char smem[44064];
    bf16* zh = (bf16*)smem;
    float* facc = (float*)smem;
    int bid = blockIdx.x;
    const Lvl P = bid < s1 ? a0 : (bid < s2 ? a1 : a2);
    int local = bid - (bid < s1 ? 0 : (bid < s2 ? s1 : s2));
    const int H = P.H, W = H, Npix = H * W, tX = P.tX;
    int tid = threadIdx.x, lane = tid & 63, wv = tid >> 6;
    int cc = wv >> 2, wv4 = wv & 3;
    int quad = lane >> 4, col = lane & 15;
    int tpi = tX * tX;
    int b = local / tpi;
    int t = local - b * tpi;
    int ty = t / tX, tx = t - ty * tX;
    int y0 = ty * 16, x0 = tx * 16;

    for (int e = tid; e < 2 * 324 * 32; e += 512) {
        int ch = e / 324, pix = e - ch * 324;
        int hy = pix / 18, hx = pix - hy * 18;
        int gy = y0 - 1 + hy, gx = x0 - 1 + hx;
        bf16 v = f2b(0.f);
        if (gy >= 0 && gy < H && gx >= 0 && gx < W)
            v = P.z[((size_t)(b * 64 + ch)) * Npix + gy * W + gx];
        zh[(ch >> 5) * 11016 + pix * 34 + (ch & 31)] = v;
    }
    __syncthreads();

    short8 Bf[9][2];
    const bf16* wp = P.Wc3 + (size_t)cc * 9216 + col * 32 + quad * 8;
#pragma unroll
    for (int tap = 0; tap < 9; tap++)
#pragma unroll
        for (int ot = 0; ot < 2; ot++)
            Bf[tap][ot] = *(const short8*)(wp + (tap * 2 + ot) * 512);

    floatx4 acc[4][2];
#pragma unroll
    for (int pt = 0; pt < 4; pt++)
#pragma unroll
        for (int ot = 0; ot < 2; ot++) acc[pt][ot] = (floatx4){0.f, 0.f, 0.f, 0.f};

    const bf16* zbp = zh + cc * 11016;
#pragma unroll
    for (int pt = 0; pt < 4; pt++) {
        int yy = wv4 * 4 + pt;
#pragma unroll
        for (int tap = 0; tap < 9; tap++) {
            int dy = tap / 3, dx = tap - dy * 3;
            short8 A = *(const short8*)(zbp + ((yy + dy) * 18 + (col + dx)) * 34 + quad * 8);
            acc[pt][0] = MFMA16(A, Bf[tap][0], acc[pt][0]);
            acc[pt][1] = MFMA16(A, Bf[tap][1], acc[pt][1]);
        }
    }
    __syncthreads();

    if (cc == 1) {
#pragma unroll
        for (int pt = 0; pt < 4; pt++)
#pragma unroll
            for (int ot = 0; ot < 2; ot++)
#pragma unroll
                for (int r = 0; r < 4; r++)
                    facc[((wv4 * 4 + pt) * 16 + quad * 4 + r) * 33 + ot * 16 + col]
                        = acc[pt][ot][r];
    }
    __syncthreads();

    if (cc == 0) {
#pragma unroll
        for (int pt = 0; pt < 4; pt++) {
            int oy = y0 + wv4 * 4 + pt;
            if (oy >= H) continue;
#pragma unroll
            for (int ot = 0; ot < 2; ot++) {
                int o = ot * 16 + col;
                size_t ob = P.outOff + (size_t)(b * 32 + o) * Npix + (size_t)oy * W;
                float bias = P.bfold[o];
#pragma unroll
                for (int r = 0; r < 4; r++) {
                    int ox = x0 + quad * 4 + r;
                    if (ox >= W) continue;
                    float a = acc[pt][ot][r] + bias
                            + facc[((wv4 * 4 + pt) * 16 + quad * 4 + r) * 33 + o];
                    if (f32) ((float*)out)[ob + ox] = a;
                    else     ((bf16*)out)[ob + ox] = f2b(a);
                }
            }
        }
    }
}

extern "C" void kernel_launch(void* const* d_in, const int* in_sizes, int n_in,
                              void* d_out, int out_size, void* d_ws, size_t ws_size,
                              hipStream_t stream)
{
    const int Hs[3] = {96, 48, 24};
    const int ss[3] = {2, 4, 8};
    const int npads[3] = {2304, 192, 64};
    const size_t outOff[3] = {0, 1179648, 1474560};
    const int BNs[3] = {36864, 9216, 2304};

    int nch[3] = {2, 2, 1};

    int* flag = (int*)d_ws;
    float* wsf = (float*)d_ws + 16;
    float* lpbase = wsf + 3 * LVS;
    size_t lpo[3], lpacc = 0;
    for (int lv = 0; lv < 3; lv++) { lpo[lv] = lpacc; lpacc += (size_t)nch[lv] * BNs[lv]; }
    bf16* bb = (bf16*)(lpbase + lpacc);

    const size_t gpo[3] = {0, 2359296, 2949120};           // 2*BN*32 each
    size_t ypo[3], ypacc = 0;
    for (int lv = 0; lv < 3; lv++) { ypo[lv] = ypacc; ypacc += (size_t)nch[lv] * BNs[lv] * 32; }
    size_t Asz = ypacc > 3096576 ? ypacc : 3096576;
    const size_t tho[3] = {0, 1179648, 1474560};
    const size_t pho[3] = {1548288, 2138112, 2187264};
    const size_t gto[3] = {1843200, 2162688, 2195456};
    const size_t zo[3]  = {0, 2359296, 2949120};

    Ptrs hp;
    for (int i = 0; i < 45 && i < n_in; i++) hp.p[i] = d_in[i];
    k_prep<<<dim3(8, 3), 256, 0, stream>>>(hp, flag, wsf);

    Lvl L[3];
    for (int lv = 0; lv < 3; lv++) {
        int H = Hs[lv], N = H * H;
        float* base = wsf + (size_t)lv * LVS;
        L[lv].f1 = d_in[2 * lv];
        L[lv].f2 = d_in[2 * lv + 1];
        L[lv].btgp = base + O_BTGP;
        L[lv].wbf = base + O_WBF;
        L[lv].bfold = base + O_BFOLD;
        L[lv].Wt = (const bf16*)(base + O_WT);
        L[lv].Wc3 = (const bf16*)(base + O_WC3);
        L[lv].Wb = (const bf16*)(base + O_WB);
        L[lv].g = bb + gpo[lv];
        L[lv].p = bb + gpo[lv] + (size_t)4 * N * 32;
        L[lv].yp = bb + ypo[lv];
        L[lv].th = bb + Asz + tho[lv];
        L[lv].phi = bb + Asz + pho[lv];
        L[lv].gt = bb + Asz + gto[lv];
        L[lv].z = bb + Asz + zo[lv];
        L[lv].lp = lpbase + lpo[lv];
        L[lv].N = N;
        L[lv].n = (H / ss[lv]) * (H / ss[lv]);
        L[lv].npad = npads[lv];
        L[lv].nch = nch[lv];
        L[lv].W = H;
        L[lv].s = ss[lv];
        L[lv].wp = H / ss[lv];
        L[lv].H = H;
        L[lv].tX = (H + 15) / 16;
        L[lv].BN = 4 * N;
        L[lv].outOff = outOff[lv];
    }

    int a0 = nch[0] * (BNs[0] >> 6), a1 = nch[1] * (BNs[1] >> 6), a2 = nch[2] * (BNs[2] >> 6);
    k_tgpm<<<756, 256, 0, stream>>>(L[0], L[1], L[2], 576, 720, flag);
    k_pool<<<1280, 256, 0, stream>>>(L[0], L[1], L[2], 1152, 1248);
    k_attn<<<a0 + a1 + a2, 256, 0, stream>>>(L[0], L[1], L[2], a0, a0 + a1);
    k_merge<<<756, 256, 0, stream>>>(L[0], L[1], L[2], 576, 720, flag);
    k_conv3m<<<196, 512, 0, stream>>>(L[0], L[1], L[2], 144, 180, d_out, flag);
}

// Round 14
// 265.269 us; speedup vs baseline: 1.0995x; 1.0995x over previous
//
#include <hip/hip_runtime.h>
#include <hip/hip_bf16.h>

typedef __hip_bfloat16 bf16;
typedef __attribute__((ext_vector_type(8))) short short8;
typedef __attribute__((ext_vector_type(4))) float floatx4;

__device__ __forceinline__ float b2f(bf16 v) { return __bfloat162float(v); }
__device__ __forceinline__ bf16 f2b(float v) { return __float2bfloat16(v); }
__device__ __forceinline__ float ldv(const void* p, size_t i, bool f32) {
    return f32 ? ((const float*)p)[i] : b2f(((const bf16*)p)[i]);
}
template <bool F32>
__device__ __forceinline__ float ldt(const void* p, size_t i) {
    return F32 ? ((const float*)p)[i] : b2f(((const bf16*)p)[i]);
}
__device__ __forceinline__ float s2f(short s) {
    unsigned int u = ((unsigned int)(unsigned short)s) << 16;
    float f; __builtin_memcpy(&f, &u, 4); return f;
}
__device__ __forceinline__ short f2s(float f) {
    bf16 h = f2b(f); short s; __builtin_memcpy(&s, &h, 2); return s;
}
__device__ __forceinline__ bool uflag(const int* flag) {
    return __builtin_amdgcn_readfirstlane(flag[0]) != 0;   // SGPR -> uniform branch
}
#define MFMA16(a, b, c) __builtin_amdgcn_mfma_f32_16x16x32_bf16(a, b, c, 0, 0, 0)

struct Ptrs { const void* p[45]; };

struct Lvl {
    const void *f1, *f2;
    const float *btgp, *wbf, *bfold;
    const bf16 *Wb, *Wt, *Wc3;
    bf16 *th, *g, *p, *phi, *gt, *yp, *z;
    float* lp;
    int N, n, npad, nch, W, s, wp, H, tX, BN;
    size_t outOff;
};

// per-level weight region layout (float offsets), stride LVS
#define O_BTGP  0
#define O_WBF   96
#define O_BFOLD 160
#define O_WT    192            // 2048 bf16 = 1024 floats
#define O_WC3   1216           // 18432 bf16 = 9216 floats
#define O_WB    10432          // 6144 bf16 = 3072 floats  (tgp weights [o][k])
#define LVS     13504

// ---------------- K0: weight prep + inline dtype detect; theta scaled by log2(e) ----------------
__global__ void k_prep(Ptrs in, int* flag, float* __restrict__ wsf)
{
    __shared__ int scnt;
    if (threadIdx.x == 0) scnt = 0;
    __syncthreads();
    {
        const unsigned short* us = (const unsigned short*)in.p[0];
        int local = 0;
        for (int i = threadIdx.x; i < 8192; i += 256) {
            unsigned e = us[2 * i] & 0x7F80u;
            if (e == 0x7F80u || e == 0u) local++;
        }
        atomicAdd(&scnt, local);
    }
    __syncthreads();
    bool f32 = scnt >= 8;
    if (blockIdx.x == 0 && blockIdx.y == 0 && threadIdx.x == 0) flag[0] = f32 ? 1 : 0;

    int lv = blockIdx.y;
    float* base = wsf + (size_t)lv * LVS;
    const int wb0 = 6 + 13 * lv;
    const void* gw  = in.p[wb0 + 0];
    const void* gb  = in.p[wb0 + 1];
    const void* tw  = in.p[wb0 + 2];
    const void* tb  = in.p[wb0 + 3];
    const void* pw  = in.p[wb0 + 4];
    const void* pb  = in.p[wb0 + 5];
    const void* ww  = in.p[wb0 + 6];
    const void* wb  = in.p[wb0 + 7];
    const void* cw  = in.p[wb0 + 8];
    const void* bng = in.p[wb0 + 9];
    const void* bnb = in.p[wb0 + 10];
    const void* bnm = in.p[wb0 + 11];
    const void* bnv = in.p[wb0 + 12];
    int gid = blockIdx.x * 256 + threadIdx.x;
    int stride = gridDim.x * 256;
    const float LOG2E = 1.44269504088896f;   // exp(f) == exp2(f*log2e); theta feeds scores only

    float* btgp = base + O_BTGP;
    float* wbf = base + O_WBF;
    float* bfold = base + O_BFOLD;
    bf16* Wt = (bf16*)(base + O_WT);
    bf16* Wc3 = (bf16*)(base + O_WC3);
    bf16* Wb = (bf16*)(base + O_WB);

    for (int e = gid; e < 96 * 64; e += stride) {
        int o = e >> 6, k = e & 63;
        float v;
        if (o < 32)      v = ldv(tw, (size_t)o * 64 + k, f32) * LOG2E;
        else if (o < 64) v = ldv(gw, (size_t)(o - 32) * 64 + k, f32);
        else             v = ldv(pw, (size_t)(o - 64) * 64 + k, f32);
        Wb[e] = f2b(v);
    }
    for (int e = gid; e < 96; e += stride) {
        float v = (e < 32) ? ldv(tb, e, f32) * LOG2E
                           : (e < 64 ? ldv(gb, e - 32, f32) : ldv(pb, e - 64, f32));
        btgp[e] = v;
    }
    for (int e = gid; e < 64 * 32; e += stride)
        Wt[e] = f2b(ldv(ww, e, f32));
    for (int e = gid; e < 64; e += stride) wbf[e] = ldv(wb, e, f32);
    for (int e = gid; e < 18432; e += stride) {
        int k = e & 31, n = (e >> 5) & 15, ot = (e >> 9) & 1;
        int tap = (e >> 10) % 9, cc = e / 9216;
        int o = ot * 16 + n, c = cc * 32 + k;
        float inv = ldv(bng, o, f32) * rsqrtf(ldv(bnv, o, f32) + 1e-5f);
        Wc3[e] = f2b(ldv(cw, ((size_t)o * 64 + c) * 9 + tap, f32) * inv);
    }
    for (int e = gid; e < 32; e += stride) {
        float inv = ldv(bng, e, f32) * rsqrtf(ldv(bnv, e, f32) + 1e-5f);
        bfold[e] = ldv(bnb, e, f32) - ldv(bnm, e, f32) * inv;
    }
}

// ---------------- K1: MFMA theta/g/phi 1x1 conv (proven) ----------------
template <bool F32>
__device__ __forceinline__ void tgpm_body(const Lvl& P, int rb)
{
    __shared__ __align__(16) bf16 X[64 * 72];
    int tid = threadIdx.x, lane = tid & 63, wv = tid >> 6;
    int quad = lane >> 4, col = lane & 15;
    int row0 = rb * 64;
    int b = row0 / P.N;
    int pix0 = row0 - b * P.N;

#pragma unroll
    for (int it = 0; it < 16; it++) {
        int e = it * 256 + tid;
        int pix = e & 63, c = e >> 6;
        const void* fx = (c < 32) ? P.f1 : P.f2;
        int cc = c & 31;
        float v = ldt<F32>(fx, (size_t)(b * 32 + cc) * P.N + pix0 + pix);
        X[pix * 72 + c] = f2b(v);
    }
    __syncthreads();

    short8 a_lo = *(const short8*)(X + (wv * 16 + col) * 72 + quad * 8);
    short8 a_hi = *(const short8*)(X + (wv * 16 + col) * 72 + 32 + quad * 8);
    const floatx4 zc = {0.f, 0.f, 0.f, 0.f};
#pragma unroll
    for (int ot = 0; ot < 6; ot++) {
        const bf16* wp = P.Wb + (size_t)(ot * 16 + col) * 64 + quad * 8;
        short8 b_lo = *(const short8*)(wp);
        short8 b_hi = *(const short8*)(wp + 32);
        floatx4 acc = MFMA16(a_lo, b_lo, zc);
        acc = MFMA16(a_hi, b_hi, acc);
        float bias = P.btgp[ot * 16 + col];
        bf16* dst = (ot < 2) ? P.th : ((ot < 4) ? P.g : P.p);
        int och = (ot & 1) * 16 + col;
#pragma unroll
        for (int r = 0; r < 4; r++) {
            int pix = row0 + wv * 16 + quad * 4 + r;
            dst[(size_t)pix * 32 + och] = f2b(acc[r] + bias);
        }
    }
}

__global__ void k_tgpm(Lvl a0, Lvl a1, Lvl a2, int s1, int s2, const int* flag)
{
    int bid = blockIdx.x;
    const Lvl P = bid < s1 ? a0 : (bid < s2 ? a1 : a2);
    int rb = bid - (bid < s1 ? 0 : (bid < s2 ? s1 : s2));
    if (uflag(flag)) tgpm_body<true>(P, rb);
    else             tgpm_body<false>(P, rb);
}

// ---------------- K2: max pool -> phiB / gT (proven) ----------------
__global__ void k_pool(Lvl a0, Lvl a1, Lvl a2, int s1, int s2)
{
    int bid = blockIdx.x;
    const Lvl P = bid < s1 ? a0 : (bid < s2 ? a1 : a2);
    int local = bid - (bid < s1 ? 0 : (bid < s2 ? s1 : s2));
    int gid = local * 256 + threadIdx.x;
    int npad = P.npad;
    if (gid >= 4 * npad * 32) return;
    int c = gid & 31;
    int j = (gid >> 5) % npad;
    int b = gid / (32 * npad);
    float mg = 0.f, mp = 0.f;
    if (j < P.n) {
        int py = j / P.wp, px = j - py * P.wp;
        const int N = P.N;
        mg = -INFINITY; mp = -INFINITY;
        for (int dy = 0; dy < P.s; dy++)
            for (int dx = 0; dx < P.s; dx++) {
                int idx = (py * P.s + dy) * P.W + px * P.s + dx;
                size_t bse = ((size_t)b * N + idx) * 32 + c;
                mg = fmaxf(mg, b2f(P.g[bse]));
                mp = fmaxf(mp, b2f(P.p[bse]));
            }
    }
    P.phi[((size_t)b * npad + j) * 32 + c] = f2b(mp);
    P.gt[((size_t)b * 32 + c) * npad + j] = f2b(mg);
}

// ---------------- K3: MFMA attention, block-cooperative LDS-staged pipeline ----------------
// Per tile the BLOCK stages phi(64x32)+g(32x64) once into padded LDS (double-
// buffered); next tile's loads issue before compute (register relay), ds_write
// after compute, one barrier per tile. exp -> exp2 (log2e folded into theta).
__launch_bounds__(256)
__global__ void k_attn(Lvl a0, Lvl a1, Lvl a2, int s1, int s2)
{
    // layout (bf16 elems): buf0 phi[64][40] (2560) + g[32][72] (2304) = 4864;
    // buf1 at 4864; Pt at 9728 (4 waves x 1152). total 14336 el = 28672 B.
    __shared__ __align__(16) bf16 smem[14336];
    int bid = blockIdx.x;
    const Lvl P = bid < s1 ? a0 : (bid < s2 ? a1 : a2);
    int local = bid - (bid < s1 ? 0 : (bid < s2 ? s1 : s2));
    int rowblocks = P.BN >> 6;
    int c = local / rowblocks;
    int rb = local - c * rowblocks;

    int tid = threadIdx.x, lane = tid & 63, wv = tid >> 6;
    int quad = lane >> 4, col = lane & 15;
    bf16* Pt = smem + 9728 + wv * 1152;
    int row0 = rb * 64;
    int b = row0 / P.N;
    int npad = P.npad;

    int T = npad >> 6, C = P.nch;
    int js = ((T * c) / C) << 6;
    int je = ((T * (c + 1)) / C) << 6;

    short8 ta = *(const short8*)(P.th + (size_t)(row0 + wv * 16 + col) * 32 + quad * 8);

    // this thread's staging slice: one 16B chunk of phi, one of g
    const bf16* phsrc = P.phi + ((size_t)b * npad + (tid >> 2)) * 32 + (tid & 3) * 8;
    const bf16* gsrc  = P.gt + ((size_t)b * 32 + (tid >> 3)) * npad + (tid & 7) * 8;
    int phdst = (tid >> 2) * 40 + (tid & 3) * 8;                 // phi[key][40]
    int gdst  = 2560 + (tid >> 3) * 72 + (tid & 7) * 8;          // g[ch][72]

    // prologue: stage tile js into buf0
    {
        short8 pv = *(const short8*)(phsrc + (size_t)js * 32);
        short8 gv = *(const short8*)(gsrc + js);
        *(short8*)(smem + phdst) = pv;
        *(short8*)(smem + gdst) = gv;
    }
    __syncthreads();

    floatx4 y0 = {0.f, 0.f, 0.f, 0.f}, y1 = {0.f, 0.f, 0.f, 0.f};
    float lp4[4] = {0.f, 0.f, 0.f, 0.f};
    const floatx4 zc = {0.f, 0.f, 0.f, 0.f};

    int cur = 0;
    for (int j0 = js; j0 < je; j0 += 64) {
        bool hasN = (j0 + 64) < je;
        short8 phN, ggN;
        if (hasN) {                                  // issue next tile's loads NOW
            phN = *(const short8*)(phsrc + (size_t)(j0 + 64) * 32);
            ggN = *(const short8*)(gsrc + j0 + 64);
        }
        const bf16* pbuf = smem + cur * 4864;
        const bf16* gbuf = pbuf + 2560;

        floatx4 s0 = MFMA16(ta, *(const short8*)(pbuf + (col) * 40 + quad * 8), zc);
        floatx4 s1 = MFMA16(ta, *(const short8*)(pbuf + (16 + col) * 40 + quad * 8), zc);
        floatx4 s2 = MFMA16(ta, *(const short8*)(pbuf + (32 + col) * 40 + quad * 8), zc);
        floatx4 s3 = MFMA16(ta, *(const short8*)(pbuf + (48 + col) * 40 + quad * 8), zc);
#pragma unroll
        for (int r = 0; r < 4; r++) {
            float p0 = exp2f(s0[r]), p1 = exp2f(s1[r]);
            float p2 = exp2f(s2[r]), p3 = exp2f(s3[r]);
            lp4[r] += (p0 + p1) + (p2 + p3);
            bf16* pr = Pt + (quad * 4 + r) * 72;
            pr[ 0 + col] = f2b(p0);
            pr[16 + col] = f2b(p1);
            pr[32 + col] = f2b(p2);
            pr[48 + col] = f2b(p3);
        }
#pragma unroll
        for (int kc = 0; kc < 2; kc++) {
            short8 pa = *(const short8*)(Pt + col * 72 + kc * 32 + quad * 8);
            short8 g0 = *(const short8*)(gbuf + col * 72 + kc * 32 + quad * 8);
            short8 g1 = *(const short8*)(gbuf + (16 + col) * 72 + kc * 32 + quad * 8);
            y0 = MFMA16(pa, g0, y0);
            y1 = MFMA16(pa, g1, y1);
        }
        if (hasN) {                                  // loads completed during compute
            *(short8*)(smem + (cur ^ 1) * 4864 + phdst) = phN;
            *(short8*)(smem + (cur ^ 1) * 4864 + gdst) = ggN;
        }
        __syncthreads();
        cur ^= 1;
    }

#pragma unroll
    for (int r = 0; r < 4; r++) {
        float v = lp4[r];
        v += __shfl_xor(v, 1); v += __shfl_xor(v, 2);
        v += __shfl_xor(v, 4); v += __shfl_xor(v, 8);
        int grow = row0 + wv * 16 + quad * 4 + r;
        size_t o = ((size_t)c * P.BN + grow) * 32;
        P.yp[o + col] = f2b(y0[r]);
        P.yp[o + 16 + col] = f2b(y1[r]);
        if (col == 0) P.lp[(size_t)c * P.BN + grow] = v;
    }
}

// ---------------- K4: merge partials + W-conv + residual -> z (proven) ----------------
__launch_bounds__(256)
__global__ void k_merge(Lvl a0, Lvl a1, Lvl a2, int s1, int s2, const int* flag)
{
    bool f32 = uflag(flag);
    __shared__ __align__(16) float zb[64 * 65];
    int bid = blockIdx.x;
    const Lvl P = bid < s1 ? a0 : (bid < s2 ? a1 : a2);
    int rb = bid - (bid < s1 ? 0 : (bid < s2 ? s1 : s2));
    int tid = threadIdx.x, lane = tid & 63, wv = tid >> 6;
    int quad = lane >> 4, col = lane & 15;
    int row0 = rb * 64;
    int b = row0 / P.N;
    int pix0 = row0 - b * P.N;

    int grow = row0 + wv * 16 + col;
    float yv[8] = {0.f, 0.f, 0.f, 0.f, 0.f, 0.f, 0.f, 0.f};
    float L = -(float)(P.npad - P.n);
    for (int cc = 0; cc < P.nch; cc++) {
        short8 v = *(const short8*)(P.yp + ((size_t)cc * P.BN + grow) * 32 + quad * 8);
#pragma unroll
        for (int j = 0; j < 8; j++) yv[j] += s2f(v[j]);
        L += P.lp[(size_t)cc * P.BN + grow];
    }
    float invL = 1.f / L;
    short8 ya;
#pragma unroll
    for (int j = 0; j < 8; j++) ya[j] = f2s(yv[j] * invL);

    const floatx4 zc = {0.f, 0.f, 0.f, 0.f};
    floatx4 zt[4];
#pragma unroll
    for (int ot = 0; ot < 4; ot++) {
        short8 wbv = *(const short8*)(P.Wt + (size_t)(ot * 16 + col) * 32 + quad * 8);
        zt[ot] = MFMA16(ya, wbv, zc);
    }
#pragma unroll
    for (int ot = 0; ot < 4; ot++)
#pragma unroll
        for (int r = 0; r < 4; r++)
            zb[(wv * 16 + quad * 4 + r) * 65 + ot * 16 + col] = zt[ot][r];
    __syncthreads();

    const void* fx = (wv < 2) ? P.f1 : P.f2;
    if (f32) {
#pragma unroll
        for (int k = 0; k < 16; k++) {
            int o = wv * 16 + k, op = o & 31;
            float a = zb[lane * 65 + o] + P.wbf[o];
            a += ((const float*)fx)[(size_t)(b * 32 + op) * P.N + pix0 + lane];
            P.z[((size_t)(b * 64 + o)) * P.N + pix0 + lane] = f2b(a);
        }
    } else {
#pragma unroll
        for (int k = 0; k < 16; k++) {
            int o = wv * 16 + k, op = o & 31;
            float a = zb[lane * 65 + o] + P.wbf[o];
            a += b2f(((const bf16*)fx)[(size_t)(b * 32 + op) * P.N + pix0 + lane]);
            P.z[((size_t)(b * 64 + o)) * P.N + pix0 + lane] = f2b(a);
        }
    }
}

// ---------------- K5: MFMA 3x3 conv, 8 waves chunk-parallel (proven) ----------------
__launch_bounds__(512)
__global__ void k_conv3m(Lvl a0, Lvl a1, Lvl a2, int s1, int s2,
                         void* out, const int* flag)
{
    bool f32 = uflag(flag);
    __shared__ __align__(16) char smem[44064];
    bf16* zh = (bf16*)smem;
    float* facc = (float*)smem;
    int bid = blockIdx.x;
    const Lvl P = bid < s1 ? a0 : (bid < s2 ? a1 : a2);
    int local = bid - (bid < s1 ? 0 : (bid < s2 ? s1 : s2));
    const int H = P.H, W = H, Npix = H * W, tX = P.tX;
    int tid = threadIdx.x, lane = tid & 63, wv = tid >> 6;
    int cc = wv >> 2, wv4 = wv & 3;
    int quad = lane >> 4, col = lane & 15;
    int tpi = tX * tX;
    int b = local / tpi;
    int t = local - b * tpi;
    int ty = t / tX, tx = t - ty * tX;
    int y0 = ty * 16, x0 = tx * 16;

    for (int e = tid; e < 2 * 324 * 32; e += 512) {
        int ch = e / 324, pix = e - ch * 324;
        int hy = pix / 18, hx = pix - hy * 18;
        int gy = y0 - 1 + hy, gx = x0 - 1 + hx;
        bf16 v = f2b(0.f);
        if (gy >= 0 && gy < H && gx >= 0 && gx < W)
            v = P.z[((size_t)(b * 64 + ch)) * Npix + gy * W + gx];
        zh[(ch >> 5) * 11016 + pix * 34 + (ch & 31)] = v;
    }
    __syncthreads();

    short8 Bf[9][2];
    const bf16* wp = P.Wc3 + (size_t)cc * 9216 + col * 32 + quad * 8;
#pragma unroll
    for (int tap = 0; tap < 9; tap++)
#pragma unroll
        for (int ot = 0; ot < 2; ot++)
            Bf[tap][ot] = *(const short8*)(wp + (tap * 2 + ot) * 512);

    floatx4 acc[4][2];
#pragma unroll
    for (int pt = 0; pt < 4; pt++)
#pragma unroll
        for (int ot = 0; ot < 2; ot++) acc[pt][ot] = (floatx4){0.f, 0.f, 0.f, 0.f};

    const bf16* zbp = zh + cc * 11016;
#pragma unroll
    for (int pt = 0; pt < 4; pt++) {
        int yy = wv4 * 4 + pt;
#pragma unroll
        for (int tap = 0; tap < 9; tap++) {
            int dy = tap / 3, dx = tap - dy * 3;
            short8 A = *(const short8*)(zbp + ((yy + dy) * 18 + (col + dx)) * 34 + quad * 8);
            acc[pt][0] = MFMA16(A, Bf[tap][0], acc[pt][0]);
            acc[pt][1] = MFMA16(A, Bf[tap][1], acc[pt][1]);
        }
    }
    __syncthreads();

    if (cc == 1) {
#pragma unroll
        for (int pt = 0; pt < 4; pt++)
#pragma unroll
            for (int ot = 0; ot < 2; ot++)
#pragma unroll
                for (int r = 0; r < 4; r++)
                    facc[((wv4 * 4 + pt) * 16 + quad * 4 + r) * 33 + ot * 16 + col]
                        = acc[pt][ot][r];
    }
    __syncthreads();

    if (cc == 0) {
#pragma unroll
        for (int pt = 0; pt < 4; pt++) {
            int oy = y0 + wv4 * 4 + pt;
            if (oy >= H) continue;
#pragma unroll
            for (int ot = 0; ot < 2; ot++) {
                int o = ot * 16 + col;
                size_t ob = P.outOff + (size_t)(b * 32 + o) * Npix + (size_t)oy * W;
                float bias = P.bfold[o];
#pragma unroll
                for (int r = 0; r < 4; r++) {
                    int ox = x0 + quad * 4 + r;
                    if (ox >= W) continue;
                    float a = acc[pt][ot][r] + bias
                            + facc[((wv4 * 4 + pt) * 16 + quad * 4 + r) * 33 + o];
                    if (f32) ((float*)out)[ob + ox] = a;
                    else     ((bf16*)out)[ob + ox] = f2b(a);
                }
            }
        }
    }
}

extern "C" void kernel_launch(void* const* d_in, const int* in_sizes, int n_in,
                              void* d_out, int out_size, void* d_ws, size_t ws_size,
                              hipStream_t stream)
{
    const int Hs[3] = {96, 48, 24};
    const int ss[3] = {2, 4, 8};
    const int npads[3] = {2304, 192, 64};
    const size_t outOff[3] = {0, 1179648, 1474560};
    const int BNs[3] = {36864, 9216, 2304};

    int nch[3] = {2, 2, 1};

    int* flag = (int*)d_ws;
    float* wsf = (float*)d_ws + 16;
    float* lpbase = wsf + 3 * LVS;
    size_t lpo[3], lpacc = 0;
    for (int lv = 0; lv < 3; lv++) { lpo[lv] = lpacc; lpacc += (size_t)nch[lv] * BNs[lv]; }
    bf16* bb = (bf16*)(lpbase + lpacc);

    const size_t gpo[3] = {0, 2359296, 2949120};           // 2*BN*32 each
    size_t ypo[3], ypacc = 0;
    for (int lv = 0; lv < 3; lv++) { ypo[lv] = ypacc; ypacc += (size_t)nch[lv] * BNs[lv] * 32; }
    size_t Asz = ypacc > 3096576 ? ypacc : 3096576;
    const size_t tho[3] = {0, 1179648, 1474560};
    const size_t pho[3] = {1548288, 2138112, 2187264};
    const size_t gto[3] = {1843200, 2162688, 2195456};
    const size_t zo[3]  = {0, 2359296, 2949120};

    Ptrs hp;
    for (int i = 0; i < 45 && i < n_in; i++) hp.p[i] = d_in[i];
    k_prep<<<dim3(8, 3), 256, 0, stream>>>(hp, flag, wsf);

    Lvl L[3];
    for (int lv = 0; lv < 3; lv++) {
        int H = Hs[lv], N = H * H;
        float* base = wsf + (size_t)lv * LVS;
        L[lv].f1 = d_in[2 * lv];
        L[lv].f2 = d_in[2 * lv + 1];
        L[lv].btgp = base + O_BTGP;
        L[lv].wbf = base + O_WBF;
        L[lv].bfold = base + O_BFOLD;
        L[lv].Wt = (const bf16*)(base + O_WT);
        L[lv].Wc3 = (const bf16*)(base + O_WC3);
        L[lv].Wb = (const bf16*)(base + O_WB);
        L[lv].g = bb + gpo[lv];
        L[lv].p = bb + gpo[lv] + (size_t)4 * N * 32;
        L[lv].yp = bb + ypo[lv];
        L[lv].th = bb + Asz + tho[lv];
        L[lv].phi = bb + Asz + pho[lv];
        L[lv].gt = bb + Asz + gto[lv];
        L[lv].z = bb + Asz + zo[lv];
        L[lv].lp = lpbase + lpo[lv];
        L[lv].N = N;
        L[lv].n = (H / ss[lv]) * (H / ss[lv]);
        L[lv].npad = npads[lv];
        L[lv].nch = nch[lv];
        L[lv].W = H;
        L[lv].s = ss[lv];
        L[lv].wp = H / ss[lv];
        L[lv].H = H;
        L[lv].tX = (H + 15) / 16;
        L[lv].BN = 4 * N;
        L[lv].outOff = outOff[lv];
    }

    int a0 = nch[0] * (BNs[0] >> 6), a1 = nch[1] * (BNs[1] >> 6), a2 = nch[2] * (BNs[2] >> 6);
    k_tgpm<<<756, 256, 0, stream>>>(L[0], L[1], L[2], 576, 720, flag);
    k_pool<<<1280, 256, 0, stream>>>(L[0], L[1], L[2], 1152, 1248);
    k_attn<<<a0 + a1 + a2, 256, 0, stream>>>(L[0], L[1], L[2], a0, a0 + a1);
    k_merge<<<756, 256, 0, stream>>>(L[0], L[1], L[2], 576, 720, flag);
    k_conv3m<<<196, 512, 0, stream>>>(L[0], L[1], L[2], 144, 180, d_out, flag);
}